// Round 7
// baseline (246.070 us; speedup 1.0000x reference)
//
#include <hip/hip_runtime.h>
#include <math.h>

#define BN_EPS 1e-5f

using short8  = __attribute__((ext_vector_type(8))) short;
using f32x16  = __attribute__((ext_vector_type(16))) float;

// ---------------------------------------------------------------------------
// x (16,640,32,32) fp32. Pixels P=16384, p = b*1024 + h*32 + w.
// ident: bf16 [p][64] pixel-major.
// feat K-order (permuted): kg'<64 -> identity ch kg'; kg'>=64: t=kg'-64,
//   ksp=t>>6 (spatial 0..24), c=t&63; orig w_emb col = 64 + c*25 + ksp.
// Weight tiles (A-frag order), per kc (K=32 chunk) 512 uint4 units:
//   u = (mf*2+kh)*64 + sl;  oc = mt*128 + mf*32 + (sl&31),
//   k = kc*32 + kh*16 + (sl>>5)*8 + j   (8 bf16 per unit)
// featG (B-frag order): [pt:256][kc:52][u:256],
//   u = (hf<<7)|(bkh<<6)|sl; px = pt*64 + hf*32 + (sl&31),
//   kg' = kc*32 + bkh*16 + (sl>>5)*8 + j
// eG (B-frag order for k_out): [pt:256][kc:20][u:256], same u scheme, k=oc.
// ---------------------------------------------------------------------------

__device__ __forceinline__ float bflo(unsigned u) { return __uint_as_float(u << 16); }
__device__ __forceinline__ float bfhi(unsigned u) { return __uint_as_float(u & 0xffff0000u); }

__device__ __forceinline__ unsigned bf16_rne(float f) {
    unsigned u = __float_as_uint(f);
    return (u + 0x7fffu + ((u >> 16) & 1u)) >> 16;
}
__device__ __forceinline__ unsigned pack_bf16(float lo, float hi) {
    return bf16_rne(lo) | (bf16_rne(hi) << 16);
}
// fast pack: round-half-up + byte-perm
__device__ __forceinline__ unsigned pk_hu(float lo, float hi) {
    unsigned a = __float_as_uint(lo) + 0x8000u;
    unsigned b = __float_as_uint(hi) + 0x8000u;
    return __builtin_amdgcn_perm(b, a, 0x07060302u);
}
__device__ __forceinline__ unsigned pmul_fast(unsigned a, unsigned b) {
    return pk_hu(bflo(a) * bflo(b), bfhi(a) * bfhi(b));
}

// ===========================================================================
// k_prep: scalars + wIt + wOt.  grid 232x256
// ===========================================================================
__global__ __launch_bounds__(256)
void k_prep(const float* __restrict__ g1, const float* __restrict__ b1,
            const float* __restrict__ m1, const float* __restrict__ v1,
            const float* __restrict__ w_in,
            const float* __restrict__ gi, const float* __restrict__ bi,
            const float* __restrict__ mi, const float* __restrict__ vi,
            const float* __restrict__ ge, const float* __restrict__ be,
            const float* __restrict__ me, const float* __restrict__ ve,
            const float* __restrict__ w_out,
            const float* __restrict__ go, const float* __restrict__ bo,
            const float* __restrict__ mo, const float* __restrict__ vo,
            float* __restrict__ s1, float* __restrict__ b1c,
            float* __restrict__ biasI, float* __restrict__ biasE, float* __restrict__ biasO,
            unsigned* __restrict__ wIt, unsigned* __restrict__ wOt)
{
    int i = blockIdx.x * 256 + threadIdx.x;

    if (i < 640) {
        float s = g1[i] * rsqrtf(v1[i] + BN_EPS);
        s1[i] = s; b1c[i] = b1[i] - m1[i] * s;
    } else if (i < 704) {
        int c = i - 640;
        float s = gi[c] * rsqrtf(vi[c] + BN_EPS);
        biasI[c] = bi[c] - mi[c] * s;
    } else if (i < 1344) {
        int c = i - 704;
        float s = ge[c] * rsqrtf(ve[c] + BN_EPS);
        biasE[c] = be[c] - me[c] * s;
    } else if (i < 1984) {
        int c = i - 1344;
        float s = go[c] * rsqrtf(vo[c] + BN_EPS);
        biasO[c] = bo[c] - mo[c] * s;
    }

    if (i >= 2048 && i < 7168) {         // wIt: 20 kc x 256 units
        int u = i - 2048;
        int kc = u >> 8, w = u & 255;
        int mf = w >> 7, kh = (w >> 6) & 1, sl = w & 63;
        int oc = mf * 32 + (sl & 31);
        int k0 = kc * 32 + kh * 16 + (sl >> 5) * 8;
        float sc = gi[oc] * rsqrtf(vi[oc] + BN_EPS);
        unsigned d[4];
#pragma unroll
        for (int q = 0; q < 4; q++)
            d[q] = pack_bf16(w_in[oc * 640 + k0 + 2 * q] * sc,
                             w_in[oc * 640 + k0 + 2 * q + 1] * sc);
        ((uint4*)wIt)[u] = make_uint4(d[0], d[1], d[2], d[3]);
    }

    if (i >= 8192 && i < 59392) {        // wOt: 5 mt x 20 kc x 512 units
        int u = i - 8192;
        int ci = u >> 9, w = u & 511;
        int mt = ci / 20, kc = ci - mt * 20;
        int mf = w >> 7, kh = (w >> 6) & 1, sl = w & 63;
        int oc = mt * 128 + mf * 32 + (sl & 31);
        int k0 = kc * 32 + kh * 16 + (sl >> 5) * 8;
        float sc = go[oc] * rsqrtf(vo[oc] + BN_EPS);
        unsigned d[4];
#pragma unroll
        for (int q = 0; q < 4; q++)
            d[q] = pack_bf16(w_out[oc * 640 + k0 + 2 * q] * sc,
                             w_out[oc * 640 + k0 + 2 * q + 1] * sc);
        ((uint4*)wOt)[u] = make_uint4(d[0], d[1], d[2], d[3]);
    }
}

// ===========================================================================
// k_prepE: wEt via per-oc LDS staged row. 640 blocks.
// ===========================================================================
__global__ __launch_bounds__(256)
void k_prepE(const float* __restrict__ w_emb,
             const float* __restrict__ ge, const float* __restrict__ ve,
             unsigned* __restrict__ wEt)
{
    __shared__ float row[1664];
    const int tid = threadIdx.x;
    const int oc = blockIdx.x;

#pragma unroll
    for (int it = 0; it < 2; it++) {
        int u = it * 256 + tid;
        if (u < 416)
            ((float4*)row)[u] = ((const float4*)&w_emb[(size_t)oc * 1664])[u];
    }
    __syncthreads();

    if (tid < 208) {
        int kc = tid >> 2, kh = (tid >> 1) & 1, ksub = tid & 1;
        int k0 = kc * 32 + kh * 16 + ksub * 8;
        float sc = ge[oc] * rsqrtf(ve[oc] + BN_EPS);
        float v[8];
#pragma unroll
        for (int j = 0; j < 8; j++) {
            int kgp = k0 + j;
            int orig;
            if (kgp < 64) orig = kgp;
            else { int t = kgp - 64; orig = 64 + (t & 63) * 25 + (t >> 6); }
            v[j] = row[orig] * sc;
        }
        int mt = oc >> 7, mf = (oc >> 5) & 3;
        int idx = (mt * 52 + kc) * 512 + (mf * 2 + kh) * 64 + ksub * 32 + (oc & 31);
        ((uint4*)wEt)[idx] = make_uint4(pack_bf16(v[0], v[1]), pack_bf16(v[2], v[3]),
                                        pack_bf16(v[4], v[5]), pack_bf16(v[6], v[7]));
    }
}

// ===========================================================================
// k_identity: 512 thr, K-split halves + fp32 LDS reduction.
// ===========================================================================
__global__ __launch_bounds__(512, 1)
void k_identity(const float* __restrict__ x,
                const float* __restrict__ s1, const float* __restrict__ b1c,
                const unsigned* __restrict__ wIt, const float* __restrict__ biasI,
                unsigned* __restrict__ ident)
{
    __shared__ short smem[2][4096];
    __shared__ float Tpart[64 * 65];
    __shared__ float T[64 * 68];
    __shared__ float inv[64];

    const int tid  = threadIdx.x;
    const int half = tid >> 8;
    const int t    = tid & 255;
    const int l = t & 63, wv = t >> 6;
    const int mf = wv >> 1, nf = wv & 1;
    const int p0 = blockIdx.x * 64;
    const int b = p0 >> 10, hw0 = p0 & 1023;

    f32x16 acc;
#pragma unroll
    for (int r = 0; r < 16; r++) acc[r] = 0.f;

    for (int i = 0; i < 10; i++) {
        const int kc = half * 10 + i;
        uint4 av = ((const uint4*)wIt)[kc * 256 + t];
        int bnf = t >> 7, bkh = (t >> 6) & 1, sl = t & 63;
        int px = bnf * 32 + (sl & 31);
        int ch0 = kc * 32 + bkh * 16 + (sl >> 5) * 8;
        float4 sA = *(const float4*)&s1[ch0], sB = *(const float4*)&s1[ch0 + 4];
        float4 bA = *(const float4*)&b1c[ch0], bB = *(const float4*)&b1c[ch0 + 4];
        float vv[8];
        const float* xp = &x[((size_t)b * 640 + ch0) * 1024 + hw0 + px];
        vv[0] = fmaxf(fmaf(xp[0], sA.x, bA.x), 0.f);
        vv[1] = fmaxf(fmaf(xp[1024], sA.y, bA.y), 0.f);
        vv[2] = fmaxf(fmaf(xp[2048], sA.z, bA.z), 0.f);
        vv[3] = fmaxf(fmaf(xp[3072], sA.w, bA.w), 0.f);
        vv[4] = fmaxf(fmaf(xp[4096], sB.x, bB.x), 0.f);
        vv[5] = fmaxf(fmaf(xp[5120], sB.y, bB.y), 0.f);
        vv[6] = fmaxf(fmaf(xp[6144], sB.z, bB.z), 0.f);
        vv[7] = fmaxf(fmaf(xp[7168], sB.w, bB.w), 0.f);
        uint4 bvpk = make_uint4(pack_bf16(vv[0], vv[1]), pack_bf16(vv[2], vv[3]),
                                pack_bf16(vv[4], vv[5]), pack_bf16(vv[6], vv[7]));
        __syncthreads();
        ((uint4*)smem[half])[t] = av;
        ((uint4*)(smem[half] + 2048))[t] = bvpk;
        __syncthreads();
#pragma unroll
        for (int kh = 0; kh < 2; kh++) {
            short8 a  = *(const short8*)&smem[half][((mf * 2 + kh) * 64 + l) * 8];
            short8 bb = *(const short8*)&smem[half][2048 + ((nf * 2 + kh) * 64 + l) * 8];
            acc = __builtin_amdgcn_mfma_f32_32x32x16_bf16(a, bb, acc, 0, 0, 0);
        }
    }
    if (half == 1) {
#pragma unroll
        for (int r = 0; r < 16; r++) {
            int m = mf * 32 + (r & 3) + 8 * (r >> 2) + 4 * (l >> 5);
            int px = nf * 32 + (l & 31);
            Tpart[px * 65 + m] = acc[r];
        }
    }
    __syncthreads();
    if (half == 0) {
#pragma unroll
        for (int r = 0; r < 16; r++) {
            int m = mf * 32 + (r & 3) + 8 * (r >> 2) + 4 * (l >> 5);
            int px = nf * 32 + (l & 31);
            float v = acc[r] + Tpart[px * 65 + m];
            T[px * 68 + m] = fmaxf(v + biasI[m], 0.f);
        }
    }
    __syncthreads();
    if (tid < 64) {
        float sum = 0.f;
#pragma unroll 8
        for (int c = 0; c < 64; c++) { float v = T[tid * 68 + c]; sum = fmaf(v, v, sum); }
        inv[tid] = 1.f / fmaxf(sqrtf(sum), 1e-12f);
    }
    __syncthreads();
    {
        int px = tid >> 3, q = tid & 7;
        float iv = inv[px];
        unsigned d[4];
#pragma unroll
        for (int t2 = 0; t2 < 4; t2++)
            d[t2] = pack_bf16(T[px * 68 + q * 8 + 2 * t2] * iv,
                              T[px * 68 + q * 8 + 2 * t2 + 1] * iv);
        *(uint4*)&ident[(size_t)(p0 + px) * 32 + q * 4] = make_uint4(d[0], d[1], d[2], d[3]);
    }
}

// ===========================================================================
// k_feat: 512 thr. slab(6x36 halo) -> invD -> ctrs -> 52 kc feat (B-frag).
// ===========================================================================
#define FS_SLAB 0
#define FS_CTRS 15552
__global__ __launch_bounds__(512, 1)
void k_feat(const unsigned* __restrict__ ident, unsigned* __restrict__ featC, int ptBase)
{
    __shared__ short smem[20160];
    __shared__ float invDs[64];

    const int tid = threadIdx.x;
    const int pt = ptBase + blockIdx.x;
    const int b = pt >> 4, r0 = (pt & 15) * 2;

#pragma unroll
    for (int it = 0; it < 4; it++) {
        int u = it * 512 + tid;
        if (u < 1728) {
            int spx = u >> 3, q = u & 7;
            int sr = spx / 36, sc = spx - sr * 36;
            int r = r0 + sr - 2, c = sc - 2;
            uint4 v = make_uint4(0u, 0u, 0u, 0u);
            if (r >= 0 && r < 32 && c >= 0 && c < 32)
                v = *(const uint4*)&ident[((size_t)(b * 1024 + r * 32 + c) * 64 + q * 8) / 2];
            *(uint4*)&smem[FS_SLAB + spx * 72 + q * 8] = v;
        }
    }
    __syncthreads();

    {
        int px = tid >> 3, part = tid & 7;
        int rh = px >> 5, rw = px & 31;
        float ctr[8];
        const unsigned* cp = (const unsigned*)&smem[FS_SLAB + ((rh + 2) * 36 + rw + 2) * 72 + part * 8];
#pragma unroll
        for (int d = 0; d < 4; d++) { ctr[2 * d] = bflo(cp[d]); ctr[2 * d + 1] = bfhi(cp[d]); }
        float sum = 0.f;
#pragma unroll
        for (int k = 0; k < 25; k++) {
            const int kh = k / 5, kw = k % 5;
            const unsigned* nb = (const unsigned*)&smem[FS_SLAB + ((rh + kh) * 36 + rw + kw) * 72 + part * 8];
#pragma unroll
            for (int d = 0; d < 4; d++) {
                float q0 = bflo(nb[d]) * ctr[2 * d];
                float q1 = bfhi(nb[d]) * ctr[2 * d + 1];
                sum = fmaf(q0, q0, sum); sum = fmaf(q1, q1, sum);
            }
        }
        sum += __shfl_xor(sum, 1);
        sum += __shfl_xor(sum, 2);
        sum += __shfl_xor(sum, 4);
        if (part == 0) invDs[px] = rsqrtf(sum + 1e-6f);
    }
    __syncthreads();

    {
        int px = tid >> 3, q = tid & 7;
        int spx = ((px >> 5) + 2) * 36 + (px & 31) + 2;
        const unsigned* src = (const unsigned*)&smem[FS_SLAB + spx * 72 + q * 8];
        float iv = invDs[px];
        unsigned d[4];
#pragma unroll
        for (int dd = 0; dd < 4; dd++)
            d[dd] = pk_hu(bflo(src[dd]) * iv, bfhi(src[dd]) * iv);
        *(uint4*)&smem[FS_CTRS + px * 72 + q * 8] = make_uint4(d[0], d[1], d[2], d[3]);
    }
    __syncthreads();

    const int t = tid & 255;
    const int hf = t >> 7, bkh = (t >> 6) & 1, sl = t & 63;
    const int pxl = hf * 32 + (sl & 31);
    const int cl = bkh * 16 + (sl >> 5) * 8;
    const int spxC = (hf + 2) * 36 + (sl & 31) + 2;
    const int kcH = tid >> 8;
    uint4* dst = (uint4*)featC + (size_t)blockIdx.x * 52 * 256 + t;

    for (int it = 0; it < 26; it++) {
        int kc = it * 2 + kcH;
        uint4 f;
        if (kc < 2) {
            f = *(const uint4*)&smem[FS_SLAB + spxC * 72 + kc * 32 + cl];
        } else {
            int idx = kc - 2;
            int ksp = idx >> 1;
            int cb = (idx & 1) * 32 + cl;
            int kho = ksp / 5, kwo = ksp - kho * 5;
            int spx = (hf + kho) * 36 + (sl & 31) + kwo;
            const unsigned* nb = (const unsigned*)&smem[FS_SLAB + spx * 72 + cb];
            const unsigned* ct = (const unsigned*)&smem[FS_CTRS + pxl * 72 + cb];
            f = make_uint4(pmul_fast(nb[0], ct[0]), pmul_fast(nb[1], ct[1]),
                           pmul_fast(nb[2], ct[2]), pmul_fast(nb[3], ct[3]));
        }
        dst[kc * 256] = f;
    }
}

// ===========================================================================
// k_emb: 512 thr, 8 waves of 64oc x 32px. Pure GEMM, compiler-scheduled loop.
// grid (nt=128, mt=5).
// ===========================================================================
__global__ __launch_bounds__(512, 2)
void k_emb(const unsigned* __restrict__ featC, const unsigned* __restrict__ wEt,
           const float* __restrict__ biasE, unsigned* __restrict__ eG, int ntBase)
{
    __shared__ short Ep[128 * 136];

    const int tid = threadIdx.x;
    const int l = tid & 63, wv = tid >> 6;
    const int mh = wv & 1, nq = wv >> 1;     // m-half (64 oc), n-quarter (32 px)
    const int ntL = blockIdx.x, mt = blockIdx.y;

    f32x16 acc[2];
#pragma unroll
    for (int i = 0; i < 2; i++)
#pragma unroll
        for (int r = 0; r < 16; r++) acc[i][r] = 0.f;

    const uint4* A = (const uint4*)wEt + (size_t)(mt * 52) * 512;
    const uint4* B = (const uint4*)featC + ((size_t)ntL * 2 + (nq >> 1)) * 52 * 256 + ((nq & 1) << 7) + l;

    for (int kc = 0; kc < 52; kc++) {
        uint4 av[2][2], bv[2];
#pragma unroll
        for (int mi = 0; mi < 2; mi++)
#pragma unroll
            for (int kh = 0; kh < 2; kh++)
                av[mi][kh] = A[(size_t)kc * 512 + (((mh * 2 + mi) * 2 + kh) << 6) + l];
#pragma unroll
        for (int kh = 0; kh < 2; kh++)
            bv[kh] = B[(size_t)kc * 256 + (kh << 6)];
#pragma unroll
        for (int kh = 0; kh < 2; kh++) {
            acc[0] = __builtin_amdgcn_mfma_f32_32x32x16_bf16(*(short8*)&av[0][kh], *(short8*)&bv[kh], acc[0], 0, 0, 0);
            acc[1] = __builtin_amdgcn_mfma_f32_32x32x16_bf16(*(short8*)&av[1][kh], *(short8*)&bv[kh], acc[1], 0, 0, 0);
        }
    }

    // ---- epilogue: bias+relu -> Ep[px][136]
#pragma unroll
    for (int mi = 0; mi < 2; mi++) {
        int px = nq * 32 + (l & 31);
#pragma unroll
        for (int r = 0; r < 16; r += 2) {
            int m = (mh * 2 + mi) * 32 + (r & 3) + 8 * (r >> 2) + 4 * (l >> 5);
            float v0 = fmaxf(acc[mi][r] + biasE[mt * 128 + m], 0.f);
            float v1 = fmaxf(acc[mi][r + 1] + biasE[mt * 128 + m + 1], 0.f);
            *(unsigned*)&Ep[px * 136 + m] = pack_bf16(v0, v1);
        }
    }
    __syncthreads();
    // ---- write e in k_out B-frag order: 2048 units / 512 thr
#pragma unroll
    for (int it = 0; it < 4; it++) {
        int w = it * 512 + tid;
        int oct = w >> 7, pxl = w & 127;
        uint4 v = *(const uint4*)&Ep[pxl * 136 + oct * 8];
        int kcp = mt * 4 + (oct >> 2);
        int bkh = (oct >> 1) & 1, ksub = oct & 1;
        int ptg = (ntBase + ntL) * 2 + (pxl >> 6);
        int hf = (pxl >> 5) & 1, sl2 = ksub * 32 + (pxl & 31);
        ((uint4*)eG)[((size_t)ptg * 20 + kcp) * 256 + (hf << 7) + (bkh << 6) + sl2] = v;
    }
}

// ===========================================================================
// k_out: 512 thr, 8 waves of 64oc x 32px. grid (128, 5).
// ===========================================================================
__global__ __launch_bounds__(512, 2)
void k_out(const unsigned* __restrict__ eG, const unsigned* __restrict__ wOt,
           const float* __restrict__ biasO, float* __restrict__ out)
{
    const int tid = threadIdx.x;
    const int l = tid & 63, wv = tid >> 6;
    const int mh = wv & 1, nq = wv >> 1;
    const int nt = blockIdx.x, mt = blockIdx.y;
    const int p0 = nt * 128;
    const int b = p0 >> 10, hw0 = p0 & 1023;

    f32x16 acc[2];
#pragma unroll
    for (int i = 0; i < 2; i++)
#pragma unroll
        for (int r = 0; r < 16; r++) acc[i][r] = 0.f;

    const uint4* A = (const uint4*)wOt + (size_t)(mt * 20) * 512;
    const uint4* B = (const uint4*)eG + ((size_t)nt * 2 + (nq >> 1)) * 20 * 256 + ((nq & 1) << 7) + l;

    for (int kc = 0; kc < 20; kc++) {
        uint4 av[2][2], bv[2];
#pragma unroll
        for (int mi = 0; mi < 2; mi++)
#pragma unroll
            for (int kh = 0; kh < 2; kh++)
                av[mi][kh] = A[(size_t)kc * 512 + (((mh * 2 + mi) * 2 + kh) << 6) + l];
#pragma unroll
        for (int kh = 0; kh < 2; kh++)
            bv[kh] = B[(size_t)kc * 256 + (kh << 6)];
#pragma unroll
        for (int kh = 0; kh < 2; kh++) {
            acc[0] = __builtin_amdgcn_mfma_f32_32x32x16_bf16(*(short8*)&av[0][kh], *(short8*)&bv[kh], acc[0], 0, 0, 0);
            acc[1] = __builtin_amdgcn_mfma_f32_32x32x16_bf16(*(short8*)&av[1][kh], *(short8*)&bv[kh], acc[1], 0, 0, 0);
        }
    }
#pragma unroll
    for (int mi = 0; mi < 2; mi++) {
        int pxl = nq * 32 + (l & 31);
#pragma unroll
        for (int r = 0; r < 16; r++) {
            int oc = mt * 128 + (mh * 2 + mi) * 32 + (r & 3) + 8 * (r >> 2) + 4 * (l >> 5);
            out[((size_t)b * 640 + oc) * 1024 + hw0 + pxl] = acc[mi][r] + biasO[oc];
        }
    }
}

// ===========================================================================
extern "C" void kernel_launch(void* const* d_in, const int* in_sizes, int n_in,
                              void* d_out, int out_size, void* d_ws, size_t ws_size,
                              hipStream_t stream)
{
    const float* x    = (const float*)d_in[0];
    const float* g1   = (const float*)d_in[1];
    const float* b1   = (const float*)d_in[2];
    const float* m1   = (const float*)d_in[3];
    const float* v1   = (const float*)d_in[4];
    const float* w_in = (const float*)d_in[5];
    const float* gi   = (const float*)d_in[6];
    const float* bi   = (const float*)d_in[7];
    const float* mi   = (const float*)d_in[8];
    const float* vi   = (const float*)d_in[9];
    const float* w_emb= (const float*)d_in[10];
    const float* ge   = (const float*)d_in[11];
    const float* be   = (const float*)d_in[12];
    const float* me   = (const float*)d_in[13];
    const float* ve   = (const float*)d_in[14];
    const float* w_out= (const float*)d_in[15];
    const float* go   = (const float*)d_in[16];
    const float* bo   = (const float*)d_in[17];
    const float* mo   = (const float*)d_in[18];
    const float* vo   = (const float*)d_in[19];

    char* ws = (char*)d_ws;
    float*    s1    = (float*)(ws + 0);
    float*    b1c   = (float*)(ws + 2560);
    float*    biasI = (float*)(ws + 5120);
    float*    biasE = (float*)(ws + 5376);
    float*    biasO = (float*)(ws + 7936);
    unsigned* wIt   = (unsigned*)(ws + 16384);
    unsigned* wOt   = (unsigned*)(ws + 98304);
    unsigned* wEt   = (unsigned*)(ws + 917504);
    unsigned* ident = (unsigned*)(ws + 3047424);
    unsigned* eG    = (unsigned*)(ws + 5144576);   // ends 26,116,096
    float*    out   = (float*)d_out;

    const size_t featFullOff = 26116096ull;
    const size_t featFullBytes = 256ull * 52 * 256 * 16;   // 54,525,952

    k_prep<<<232, 256, 0, stream>>>(g1, b1, m1, v1, w_in, gi, bi, mi, vi,
                                    ge, be, me, ve, w_out, go, bo, mo, vo,
                                    s1, b1c, biasI, biasE, biasO, wIt, wOt);
    k_prepE<<<640, 256, 0, stream>>>(w_emb, ge, ve, wEt);
    k_identity<<<256, 512, 0, stream>>>(x, s1, b1c, wIt, biasI, ident);

    if (ws_size >= featFullOff + featFullBytes) {
        unsigned* featC = (unsigned*)(ws + featFullOff);
        k_feat<<<256, 512, 0, stream>>>(ident, featC, 0);
        k_emb<<<dim3(128, 5), 512, 0, stream>>>(featC, wEt, biasE, eG, 0);
    } else {
        unsigned* featC = (unsigned*)(ws + 16384);
        for (int c = 0; c < 64; c++) {
            k_feat<<<4, 512, 0, stream>>>(ident, featC, c * 4);
            k_emb<<<dim3(2, 5), 512, 0, stream>>>(featC, wEt, biasE, eG, c * 2);
        }
        k_prep<<<232, 256, 0, stream>>>(g1, b1, m1, v1, w_in, gi, bi, mi, vi,
                                        ge, be, me, ve, w_out, go, bo, mo, vo,
                                        s1, b1c, biasI, biasE, biasO, wIt, wOt);
    }
    k_out<<<dim3(128, 5), 512, 0, stream>>>(eG, wOt, biasO, out);
}

// Round 8
// 220.635 us; speedup vs baseline: 1.1153x; 1.1153x over previous
//
#include <hip/hip_runtime.h>
#include <math.h>

#define BN_EPS 1e-5f

using short8  = __attribute__((ext_vector_type(8))) short;
using f32x16  = __attribute__((ext_vector_type(16))) float;

// ---------------------------------------------------------------------------
// x (16,640,32,32) fp32. Pixels P=16384, p = b*1024 + h*32 + w.
// ident: bf16 [p][64] pixel-major.
// feat K-order (permuted): kg'<64 -> identity ch kg'; kg'>=64: t=kg'-64,
//   ksp=t>>6 (spatial 0..24), c=t&63; orig w_emb col = 64 + c*25 + ksp.
// Weight tiles (A-frag order), per kc (K=32 chunk) 512 uint4 units:
//   u = (mf*2+kh)*64 + sl;  oc = mt*128 + mf*32 + (sl&31),
//   k = kc*32 + kh*16 + (sl>>5)*8 + j
// featG (B-frag order): [pt:256][kc:52][u:256],
//   u = (hf<<7)|(bkh<<6)|sl; px = pt*64 + hf*32 + (sl&31),
//   kg' = kc*32 + bkh*16 + (sl>>5)*8 + j
// eG (B-frag order for k_out): [pt:256][kc:20][u:256], same u scheme, k=oc.
// ---------------------------------------------------------------------------

__device__ __forceinline__ float bflo(unsigned u) { return __uint_as_float(u << 16); }
__device__ __forceinline__ float bfhi(unsigned u) { return __uint_as_float(u & 0xffff0000u); }

__device__ __forceinline__ unsigned bf16_rne(float f) {
    unsigned u = __float_as_uint(f);
    return (u + 0x7fffu + ((u >> 16) & 1u)) >> 16;
}
__device__ __forceinline__ unsigned pack_bf16(float lo, float hi) {
    return bf16_rne(lo) | (bf16_rne(hi) << 16);
}
__device__ __forceinline__ unsigned pk_hu(float lo, float hi) {
    unsigned a = __float_as_uint(lo) + 0x8000u;
    unsigned b = __float_as_uint(hi) + 0x8000u;
    return __builtin_amdgcn_perm(b, a, 0x07060302u);
}
__device__ __forceinline__ unsigned pmul_fast(unsigned a, unsigned b) {
    return pk_hu(bflo(a) * bflo(b), bfhi(a) * bfhi(b));
}

// ===========================================================================
// k_prepAll: blocks [0,640) build wEt (per-oc row staging);
//            blocks [640,872) do scalars + wIt + wOt.
// ===========================================================================
__global__ __launch_bounds__(256)
void k_prepAll(const float* __restrict__ g1, const float* __restrict__ b1,
               const float* __restrict__ m1, const float* __restrict__ v1,
               const float* __restrict__ w_in,
               const float* __restrict__ gi, const float* __restrict__ bi,
               const float* __restrict__ mi, const float* __restrict__ vi,
               const float* __restrict__ w_emb,
               const float* __restrict__ ge, const float* __restrict__ be,
               const float* __restrict__ me, const float* __restrict__ ve,
               const float* __restrict__ w_out,
               const float* __restrict__ go, const float* __restrict__ bo,
               const float* __restrict__ mo, const float* __restrict__ vo,
               float* __restrict__ s1, float* __restrict__ b1c,
               float* __restrict__ biasI, float* __restrict__ biasE, float* __restrict__ biasO,
               unsigned* __restrict__ wIt, unsigned* __restrict__ wEt, unsigned* __restrict__ wOt)
{
    __shared__ float row[1664];
    const int tid = threadIdx.x;

    if (blockIdx.x < 640) {
        const int oc = blockIdx.x;
#pragma unroll
        for (int it = 0; it < 2; it++) {
            int u = it * 256 + tid;
            if (u < 416)
                ((float4*)row)[u] = ((const float4*)&w_emb[(size_t)oc * 1664])[u];
        }
        __syncthreads();
        if (tid < 208) {
            int kc = tid >> 2, kh = (tid >> 1) & 1, ksub = tid & 1;
            int k0 = kc * 32 + kh * 16 + ksub * 8;
            float sc = ge[oc] * rsqrtf(ve[oc] + BN_EPS);
            float v[8];
#pragma unroll
            for (int j = 0; j < 8; j++) {
                int kgp = k0 + j;
                int orig;
                if (kgp < 64) orig = kgp;
                else { int t = kgp - 64; orig = 64 + (t & 63) * 25 + (t >> 6); }
                v[j] = row[orig] * sc;
            }
            int mt = oc >> 7, mf = (oc >> 5) & 3;
            int idx = (mt * 52 + kc) * 512 + (mf * 2 + kh) * 64 + ksub * 32 + (oc & 31);
            ((uint4*)wEt)[idx] = make_uint4(pack_bf16(v[0], v[1]), pack_bf16(v[2], v[3]),
                                            pack_bf16(v[4], v[5]), pack_bf16(v[6], v[7]));
        }
        return;
    }

    int i = (blockIdx.x - 640) * 256 + tid;

    if (i < 640) {
        float s = g1[i] * rsqrtf(v1[i] + BN_EPS);
        s1[i] = s; b1c[i] = b1[i] - m1[i] * s;
    } else if (i < 704) {
        int c = i - 640;
        float s = gi[c] * rsqrtf(vi[c] + BN_EPS);
        biasI[c] = bi[c] - mi[c] * s;
    } else if (i < 1344) {
        int c = i - 704;
        float s = ge[c] * rsqrtf(ve[c] + BN_EPS);
        biasE[c] = be[c] - me[c] * s;
    } else if (i < 1984) {
        int c = i - 1344;
        float s = go[c] * rsqrtf(vo[c] + BN_EPS);
        biasO[c] = bo[c] - mo[c] * s;
    }

    if (i >= 2048 && i < 7168) {         // wIt
        int u = i - 2048;
        int kc = u >> 8, w = u & 255;
        int mf = w >> 7, kh = (w >> 6) & 1, sl = w & 63;
        int oc = mf * 32 + (sl & 31);
        int k0 = kc * 32 + kh * 16 + (sl >> 5) * 8;
        float sc = gi[oc] * rsqrtf(vi[oc] + BN_EPS);
        unsigned d[4];
#pragma unroll
        for (int q = 0; q < 4; q++)
            d[q] = pack_bf16(w_in[oc * 640 + k0 + 2 * q] * sc,
                             w_in[oc * 640 + k0 + 2 * q + 1] * sc);
        ((uint4*)wIt)[u] = make_uint4(d[0], d[1], d[2], d[3]);
    }

    if (i >= 8192 && i < 59392) {        // wOt
        int u = i - 8192;
        int ci = u >> 9, w = u & 511;
        int mt = ci / 20, kc = ci - mt * 20;
        int mf = w >> 7, kh = (w >> 6) & 1, sl = w & 63;
        int oc = mt * 128 + mf * 32 + (sl & 31);
        int k0 = kc * 32 + kh * 16 + (sl >> 5) * 8;
        float sc = go[oc] * rsqrtf(vo[oc] + BN_EPS);
        unsigned d[4];
#pragma unroll
        for (int q = 0; q < 4; q++)
            d[q] = pack_bf16(w_out[oc * 640 + k0 + 2 * q] * sc,
                             w_out[oc * 640 + k0 + 2 * q + 1] * sc);
        ((uint4*)wOt)[u] = make_uint4(d[0], d[1], d[2], d[3]);
    }
}

// ===========================================================================
// k_identity: 512 thr, K-split halves + fp32 LDS reduction.
// ===========================================================================
__global__ __launch_bounds__(512, 1)
void k_identity(const float* __restrict__ x,
                const float* __restrict__ s1, const float* __restrict__ b1c,
                const unsigned* __restrict__ wIt, const float* __restrict__ biasI,
                unsigned* __restrict__ ident)
{
    __shared__ short smem[2][4096];
    __shared__ float Tpart[64 * 65];
    __shared__ float T[64 * 68];
    __shared__ float inv[64];

    const int tid  = threadIdx.x;
    const int half = tid >> 8;
    const int t    = tid & 255;
    const int l = t & 63, wv = t >> 6;
    const int mf = wv >> 1, nf = wv & 1;
    const int p0 = blockIdx.x * 64;
    const int b = p0 >> 10, hw0 = p0 & 1023;

    f32x16 acc;
#pragma unroll
    for (int r = 0; r < 16; r++) acc[r] = 0.f;

    for (int i = 0; i < 10; i++) {
        const int kc = half * 10 + i;
        uint4 av = ((const uint4*)wIt)[kc * 256 + t];
        int bnf = t >> 7, bkh = (t >> 6) & 1, sl = t & 63;
        int px = bnf * 32 + (sl & 31);
        int ch0 = kc * 32 + bkh * 16 + (sl >> 5) * 8;
        float4 sA = *(const float4*)&s1[ch0], sB = *(const float4*)&s1[ch0 + 4];
        float4 bA = *(const float4*)&b1c[ch0], bB = *(const float4*)&b1c[ch0 + 4];
        float vv[8];
        const float* xp = &x[((size_t)b * 640 + ch0) * 1024 + hw0 + px];
        vv[0] = fmaxf(fmaf(xp[0], sA.x, bA.x), 0.f);
        vv[1] = fmaxf(fmaf(xp[1024], sA.y, bA.y), 0.f);
        vv[2] = fmaxf(fmaf(xp[2048], sA.z, bA.z), 0.f);
        vv[3] = fmaxf(fmaf(xp[3072], sA.w, bA.w), 0.f);
        vv[4] = fmaxf(fmaf(xp[4096], sB.x, bB.x), 0.f);
        vv[5] = fmaxf(fmaf(xp[5120], sB.y, bB.y), 0.f);
        vv[6] = fmaxf(fmaf(xp[6144], sB.z, bB.z), 0.f);
        vv[7] = fmaxf(fmaf(xp[7168], sB.w, bB.w), 0.f);
        uint4 bvpk = make_uint4(pack_bf16(vv[0], vv[1]), pack_bf16(vv[2], vv[3]),
                                pack_bf16(vv[4], vv[5]), pack_bf16(vv[6], vv[7]));
        __syncthreads();
        ((uint4*)smem[half])[t] = av;
        ((uint4*)(smem[half] + 2048))[t] = bvpk;
        __syncthreads();
#pragma unroll
        for (int kh = 0; kh < 2; kh++) {
            short8 a  = *(const short8*)&smem[half][((mf * 2 + kh) * 64 + l) * 8];
            short8 bb = *(const short8*)&smem[half][2048 + ((nf * 2 + kh) * 64 + l) * 8];
            acc = __builtin_amdgcn_mfma_f32_32x32x16_bf16(a, bb, acc, 0, 0, 0);
        }
    }
    if (half == 1) {
#pragma unroll
        for (int r = 0; r < 16; r++) {
            int m = mf * 32 + (r & 3) + 8 * (r >> 2) + 4 * (l >> 5);
            int px = nf * 32 + (l & 31);
            Tpart[px * 65 + m] = acc[r];
        }
    }
    __syncthreads();
    if (half == 0) {
#pragma unroll
        for (int r = 0; r < 16; r++) {
            int m = mf * 32 + (r & 3) + 8 * (r >> 2) + 4 * (l >> 5);
            int px = nf * 32 + (l & 31);
            float v = acc[r] + Tpart[px * 65 + m];
            T[px * 68 + m] = fmaxf(v + biasI[m], 0.f);
        }
    }
    __syncthreads();
    if (tid < 64) {
        float sum = 0.f;
#pragma unroll 8
        for (int c = 0; c < 64; c++) { float v = T[tid * 68 + c]; sum = fmaf(v, v, sum); }
        inv[tid] = 1.f / fmaxf(sqrtf(sum), 1e-12f);
    }
    __syncthreads();
    {
        int px = tid >> 3, q = tid & 7;
        float iv = inv[px];
        unsigned d[4];
#pragma unroll
        for (int t2 = 0; t2 < 4; t2++)
            d[t2] = pack_bf16(T[px * 68 + q * 8 + 2 * t2] * iv,
                              T[px * 68 + q * 8 + 2 * t2 + 1] * iv);
        *(uint4*)&ident[(size_t)(p0 + px) * 32 + q * 4] = make_uint4(d[0], d[1], d[2], d[3]);
    }
}

// ===========================================================================
// k_feat: 512 thr. slab(6x36 halo) -> invD -> ctrs -> 52 kc feat (B-frag).
// ===========================================================================
#define FS_SLAB 0
#define FS_CTRS 15552
__global__ __launch_bounds__(512, 1)
void k_feat(const unsigned* __restrict__ ident, unsigned* __restrict__ featC, int ptBase)
{
    __shared__ short smem[20160];
    __shared__ float invDs[64];

    const int tid = threadIdx.x;
    const int pt = ptBase + blockIdx.x;
    const int b = pt >> 4, r0 = (pt & 15) * 2;

#pragma unroll
    for (int it = 0; it < 4; it++) {
        int u = it * 512 + tid;
        if (u < 1728) {
            int spx = u >> 3, q = u & 7;
            int sr = spx / 36, sc = spx - sr * 36;
            int r = r0 + sr - 2, c = sc - 2;
            uint4 v = make_uint4(0u, 0u, 0u, 0u);
            if (r >= 0 && r < 32 && c >= 0 && c < 32)
                v = *(const uint4*)&ident[((size_t)(b * 1024 + r * 32 + c) * 64 + q * 8) / 2];
            *(uint4*)&smem[FS_SLAB + spx * 72 + q * 8] = v;
        }
    }
    __syncthreads();

    {
        int px = tid >> 3, part = tid & 7;
        int rh = px >> 5, rw = px & 31;
        float ctr[8];
        const unsigned* cp = (const unsigned*)&smem[FS_SLAB + ((rh + 2) * 36 + rw + 2) * 72 + part * 8];
#pragma unroll
        for (int d = 0; d < 4; d++) { ctr[2 * d] = bflo(cp[d]); ctr[2 * d + 1] = bfhi(cp[d]); }
        float sum = 0.f;
#pragma unroll
        for (int k = 0; k < 25; k++) {
            const int kh = k / 5, kw = k % 5;
            const unsigned* nb = (const unsigned*)&smem[FS_SLAB + ((rh + kh) * 36 + rw + kw) * 72 + part * 8];
#pragma unroll
            for (int d = 0; d < 4; d++) {
                float q0 = bflo(nb[d]) * ctr[2 * d];
                float q1 = bfhi(nb[d]) * ctr[2 * d + 1];
                sum = fmaf(q0, q0, sum); sum = fmaf(q1, q1, sum);
            }
        }
        sum += __shfl_xor(sum, 1);
        sum += __shfl_xor(sum, 2);
        sum += __shfl_xor(sum, 4);
        if (part == 0) invDs[px] = rsqrtf(sum + 1e-6f);
    }
    __syncthreads();

    {
        int px = tid >> 3, q = tid & 7;
        int spx = ((px >> 5) + 2) * 36 + (px & 31) + 2;
        const unsigned* src = (const unsigned*)&smem[FS_SLAB + spx * 72 + q * 8];
        float iv = invDs[px];
        unsigned d[4];
#pragma unroll
        for (int dd = 0; dd < 4; dd++)
            d[dd] = pk_hu(bflo(src[dd]) * iv, bfhi(src[dd]) * iv);
        *(uint4*)&smem[FS_CTRS + px * 72 + q * 8] = make_uint4(d[0], d[1], d[2], d[3]);
    }
    __syncthreads();

    const int t = tid & 255;
    const int hf = t >> 7, bkh = (t >> 6) & 1, sl = t & 63;
    const int pxl = hf * 32 + (sl & 31);
    const int cl = bkh * 16 + (sl >> 5) * 8;
    const int spxC = (hf + 2) * 36 + (sl & 31) + 2;
    const int kcH = tid >> 8;
    uint4* dst = (uint4*)featC + (size_t)blockIdx.x * 52 * 256 + t;

    for (int it = 0; it < 26; it++) {
        int kc = it * 2 + kcH;
        uint4 f;
        if (kc < 2) {
            f = *(const uint4*)&smem[FS_SLAB + spxC * 72 + kc * 32 + cl];
        } else {
            int idx = kc - 2;
            int ksp = idx >> 1;
            int cb = (idx & 1) * 32 + cl;
            int kho = ksp / 5, kwo = ksp - kho * 5;
            int spx = (hf + kho) * 36 + (sl & 31) + kwo;
            const unsigned* nb = (const unsigned*)&smem[FS_SLAB + spx * 72 + cb];
            const unsigned* ct = (const unsigned*)&smem[FS_CTRS + pxl * 72 + cb];
            f = make_uint4(pmul_fast(nb[0], ct[0]), pmul_fast(nb[1], ct[1]),
                           pmul_fast(nb[2], ct[2]), pmul_fast(nb[3], ct[3]));
        }
        dst[kc * 256] = f;
    }
}

// ===========================================================================
// k_emb: 128 thr = 2 waves, each 64oc x 64px. 64-px tiles.
// grid (nt=256 local, mt=5) = 1280 blocks (5/CU, balanced).
// ===========================================================================
__global__ __launch_bounds__(128, 3)
void k_emb(const unsigned* __restrict__ featC, const unsigned* __restrict__ wEt,
           const float* __restrict__ biasE, unsigned* __restrict__ eG, int ntBase)
{
    __shared__ short Ep[64 * 136];

    const int tid = threadIdx.x;
    const int l = tid & 63, mh = tid >> 6;   // wave = oc half
    const int ntL = blockIdx.x, mt = blockIdx.y;

    f32x16 acc[2][2];
#pragma unroll
    for (int i = 0; i < 2; i++)
#pragma unroll
        for (int j = 0; j < 2; j++)
#pragma unroll
            for (int r = 0; r < 16; r++) acc[i][j][r] = 0.f;

    const uint4* A = (const uint4*)wEt + (size_t)(mt * 52) * 512;
    const uint4* B = (const uint4*)featC + (size_t)ntL * 52 * 256;

    for (int kc = 0; kc < 52; kc++) {
        uint4 av[2][2], bv[2][2];
#pragma unroll
        for (int mi = 0; mi < 2; mi++)
#pragma unroll
            for (int kh = 0; kh < 2; kh++)
                av[mi][kh] = A[(size_t)kc * 512 + (((mh * 2 + mi) * 2 + kh) << 6) + l];
#pragma unroll
        for (int ni = 0; ni < 2; ni++)
#pragma unroll
            for (int kh = 0; kh < 2; kh++)
                bv[ni][kh] = B[(size_t)kc * 256 + (ni << 7) + (kh << 6) + l];
#pragma unroll
        for (int kh = 0; kh < 2; kh++) {
            acc[0][0] = __builtin_amdgcn_mfma_f32_32x32x16_bf16(*(short8*)&av[0][kh], *(short8*)&bv[0][kh], acc[0][0], 0, 0, 0);
            acc[0][1] = __builtin_amdgcn_mfma_f32_32x32x16_bf16(*(short8*)&av[0][kh], *(short8*)&bv[1][kh], acc[0][1], 0, 0, 0);
            acc[1][0] = __builtin_amdgcn_mfma_f32_32x32x16_bf16(*(short8*)&av[1][kh], *(short8*)&bv[0][kh], acc[1][0], 0, 0, 0);
            acc[1][1] = __builtin_amdgcn_mfma_f32_32x32x16_bf16(*(short8*)&av[1][kh], *(short8*)&bv[1][kh], acc[1][1], 0, 0, 0);
        }
    }

    // ---- epilogue: bias+relu -> Ep[px][136]
#pragma unroll
    for (int mi = 0; mi < 2; mi++)
#pragma unroll
        for (int ni = 0; ni < 2; ni++) {
            int px = ni * 32 + (l & 31);
#pragma unroll
            for (int r = 0; r < 16; r += 2) {
                int m = (mh * 2 + mi) * 32 + (r & 3) + 8 * (r >> 2) + 4 * (l >> 5);
                float v0 = fmaxf(acc[mi][ni][r] + biasE[mt * 128 + m], 0.f);
                float v1 = fmaxf(acc[mi][ni][r + 1] + biasE[mt * 128 + m + 1], 0.f);
                *(unsigned*)&Ep[px * 136 + m] = pack_bf16(v0, v1);
            }
        }
    __syncthreads();
    // ---- write e in k_out B-frag order: 1024 units / 128 thr
    const int ptg = ntBase + ntL;
#pragma unroll
    for (int it = 0; it < 8; it++) {
        int w = it * 128 + tid;
        int oct = w >> 6, pxl = w & 63;
        uint4 v = *(const uint4*)&Ep[pxl * 136 + oct * 8];
        int kcp = mt * 4 + (oct >> 2);
        int bkh = (oct >> 1) & 1, ksub = oct & 1;
        int hf = pxl >> 5, sl2 = ksub * 32 + (pxl & 31);
        ((uint4*)eG)[((size_t)ptg * 20 + kcp) * 256 + (hf << 7) + (bkh << 6) + sl2] = v;
    }
}

// ===========================================================================
// k_out: 128 thr = 2 waves, each 64oc x 64px. grid (256, 5).
// ===========================================================================
__global__ __launch_bounds__(128, 3)
void k_out(const unsigned* __restrict__ eG, const unsigned* __restrict__ wOt,
           const float* __restrict__ biasO, float* __restrict__ out)
{
    const int tid = threadIdx.x;
    const int l = tid & 63, mh = tid >> 6;
    const int nt = blockIdx.x, mt = blockIdx.y;
    const int p0 = nt * 64;
    const int b = p0 >> 10, hw0 = p0 & 1023;

    f32x16 acc[2][2];
#pragma unroll
    for (int i = 0; i < 2; i++)
#pragma unroll
        for (int j = 0; j < 2; j++)
#pragma unroll
            for (int r = 0; r < 16; r++) acc[i][j][r] = 0.f;

    const uint4* A = (const uint4*)wOt + (size_t)(mt * 20) * 512;
    const uint4* B = (const uint4*)eG + (size_t)nt * 20 * 256;

    for (int kc = 0; kc < 20; kc++) {
        uint4 av[2][2], bv[2][2];
#pragma unroll
        for (int mi = 0; mi < 2; mi++)
#pragma unroll
            for (int kh = 0; kh < 2; kh++)
                av[mi][kh] = A[(size_t)kc * 512 + (((mh * 2 + mi) * 2 + kh) << 6) + l];
#pragma unroll
        for (int ni = 0; ni < 2; ni++)
#pragma unroll
            for (int kh = 0; kh < 2; kh++)
                bv[ni][kh] = B[(size_t)kc * 256 + (ni << 7) + (kh << 6) + l];
#pragma unroll
        for (int kh = 0; kh < 2; kh++) {
            acc[0][0] = __builtin_amdgcn_mfma_f32_32x32x16_bf16(*(short8*)&av[0][kh], *(short8*)&bv[0][kh], acc[0][0], 0, 0, 0);
            acc[0][1] = __builtin_amdgcn_mfma_f32_32x32x16_bf16(*(short8*)&av[0][kh], *(short8*)&bv[1][kh], acc[0][1], 0, 0, 0);
            acc[1][0] = __builtin_amdgcn_mfma_f32_32x32x16_bf16(*(short8*)&av[1][kh], *(short8*)&bv[0][kh], acc[1][0], 0, 0, 0);
            acc[1][1] = __builtin_amdgcn_mfma_f32_32x32x16_bf16(*(short8*)&av[1][kh], *(short8*)&bv[1][kh], acc[1][1], 0, 0, 0);
        }
    }
#pragma unroll
    for (int mi = 0; mi < 2; mi++)
#pragma unroll
        for (int ni = 0; ni < 2; ni++) {
            int pxl = ni * 32 + (l & 31);
#pragma unroll
            for (int r = 0; r < 16; r++) {
                int oc = mt * 128 + (mh * 2 + mi) * 32 + (r & 3) + 8 * (r >> 2) + 4 * (l >> 5);
                out[((size_t)b * 640 + oc) * 1024 + hw0 + pxl] = acc[mi][ni][r] + biasO[oc];
            }
        }
}

// ===========================================================================
extern "C" void kernel_launch(void* const* d_in, const int* in_sizes, int n_in,
                              void* d_out, int out_size, void* d_ws, size_t ws_size,
                              hipStream_t stream)
{
    const float* x    = (const float*)d_in[0];
    const float* g1   = (const float*)d_in[1];
    const float* b1   = (const float*)d_in[2];
    const float* m1   = (const float*)d_in[3];
    const float* v1   = (const float*)d_in[4];
    const float* w_in = (const float*)d_in[5];
    const float* gi   = (const float*)d_in[6];
    const float* bi   = (const float*)d_in[7];
    const float* mi   = (const float*)d_in[8];
    const float* vi   = (const float*)d_in[9];
    const float* w_emb= (const float*)d_in[10];
    const float* ge   = (const float*)d_in[11];
    const float* be   = (const float*)d_in[12];
    const float* me   = (const float*)d_in[13];
    const float* ve   = (const float*)d_in[14];
    const float* w_out= (const float*)d_in[15];
    const float* go   = (const float*)d_in[16];
    const float* bo   = (const float*)d_in[17];
    const float* mo   = (const float*)d_in[18];
    const float* vo   = (const float*)d_in[19];

    char* ws = (char*)d_ws;
    float*    s1    = (float*)(ws + 0);
    float*    b1c   = (float*)(ws + 2560);
    float*    biasI = (float*)(ws + 5120);
    float*    biasE = (float*)(ws + 5376);
    float*    biasO = (float*)(ws + 7936);
    unsigned* wIt   = (unsigned*)(ws + 16384);
    unsigned* wOt   = (unsigned*)(ws + 98304);
    unsigned* wEt   = (unsigned*)(ws + 917504);
    unsigned* ident = (unsigned*)(ws + 3047424);
    unsigned* eG    = (unsigned*)(ws + 5144576);   // ends 26,116,096
    float*    out   = (float*)d_out;

    const size_t featFullOff = 26116096ull;
    const size_t featFullBytes = 256ull * 52 * 256 * 16;   // 54,525,952

    k_prepAll<<<872, 256, 0, stream>>>(g1, b1, m1, v1, w_in, gi, bi, mi, vi,
                                       w_emb, ge, be, me, ve, w_out, go, bo, mo, vo,
                                       s1, b1c, biasI, biasE, biasO, wIt, wEt, wOt);
    k_identity<<<256, 512, 0, stream>>>(x, s1, b1c, wIt, biasI, ident);

    if (ws_size >= featFullOff + featFullBytes) {
        unsigned* featC = (unsigned*)(ws + featFullOff);
        k_feat<<<256, 512, 0, stream>>>(ident, featC, 0);
        k_emb<<<dim3(256, 5), 128, 0, stream>>>(featC, wEt, biasE, eG, 0);
    } else {
        // chunked fallback: featG chunk (4 tiles) in dead wIt/wOt region;
        // wOt regenerated afterwards by re-running k_prepAll.
        unsigned* featC = (unsigned*)(ws + 16384);
        for (int c = 0; c < 64; c++) {
            k_feat<<<4, 512, 0, stream>>>(ident, featC, c * 4);
            k_emb<<<dim3(4, 5), 128, 0, stream>>>(featC, wEt, biasE, eG, c * 4);
        }
        k_prepAll<<<872, 256, 0, stream>>>(g1, b1, m1, v1, w_in, gi, bi, mi, vi,
                                           w_emb, ge, be, me, ve, w_out, go, bo, mo, vo,
                                           s1, b1c, biasI, biasE, biasO, wIt, wEt, wOt);
    }
    k_out<<<dim3(256, 5), 128, 0, stream>>>(eG, wOt, biasO, out);
}